// Round 8
// baseline (649.613 us; speedup 1.0000x reference)
//
#include <hip/hip_runtime.h>
#include <math.h>

static constexpr int BATCH = 16384;

typedef __attribute__((ext_vector_type(8))) __bf16 bf16x8;
typedef __attribute__((ext_vector_type(4))) float f32x4;

__device__ __forceinline__ float sigm(float x) { return 1.0f / (1.0f + expf(-x)); }

__device__ __forceinline__ unsigned short f2bf(float f) {
  unsigned u = __float_as_uint(f);
  return (unsigned short)((u + 0x7fffu + ((u >> 16) & 1u)) >> 16);
}
__device__ __forceinline__ float bf2f(unsigned short u) {
  return __uint_as_float((unsigned)u << 16);
}

// ---------------------------------------------------------------------------
// mgemm8: 256x256 tile, BK=32, K-span 1024 (NT=32), 8 waves (2M x 4N),
// per-wave 128x64 output (acc[8][4]).
// r6-VERIFIED SYNC SKELETON (3 barriers/tile, phase-split MFMA clusters,
// lgkm+sched_barrier guards, setprio) with ONE dataflow change:
// B is NOT staged in LDS. Each wave loads its B fragments directly from
// global (L2/L3-hot; per-wave-load = 16 fully-used 64B lines). LDS halves
// to a 4-ring of A only (64 KiB); LDS read traffic drops 96->64
// b128/CU/tile (the dominant pipe).
// vmcnt ledger (in-order retire): per tile issue [B(t) x4, stageA(t+2) x2];
// survivors entering = [A(t+1) x2]; mid-tile vmcnt(2) retires exactly
// {A(t+1), B(t)}, keeps A(t+2) in flight (never 0 in steady state).
// Tails t>=NT-2: vmcnt(0). Prologue vmcnt(2) retires A(0).
// HISTORY (do not re-try): r4 single-barrier merge = slower; r5 XCD block
// swizzle = slower + write amplification; r7 all-reads-up-front+lgkm(4) =
// slower.
// EPI 0: bf16 transposed outputs (+bias) -> t0/t1/t2 [f][b]
// EPI 1: outT[gcol][grow..] = bf16( lr * (vTin - (acc+bias)) )
// EPI 2: Cf[grow][gcol] = acc + bias  (fp32 row-major)
// EPI 3: Cf + z*1M : [grow][gcol] = acc  (fp32 P slice, kz = z*1024)
// ---------------------------------------------------------------------------
template <int EPI>
__global__ __launch_bounds__(512, 2) void mgemm8(
    const unsigned short* __restrict__ Ag, const unsigned short* __restrict__ Bg,
    int lda, int ldb, const float* __restrict__ bias,
    unsigned short* __restrict__ t0, unsigned short* __restrict__ t1,
    unsigned short* __restrict__ t2, float* __restrict__ Cf,
    const unsigned short* __restrict__ vTin, const float* __restrict__ lrp,
    unsigned short* __restrict__ outT, int ldT) {
  constexpr int NT = 32;  // K-span 1024 / BK 32
  __shared__ unsigned short As[4 * 8192];  // 4-ring x 256x32 bf16, A only (64 KiB)
  const int tid = threadIdx.x, lane = tid & 63, w = tid >> 6;
  const int lm = lane & 15, kg = lane >> 4;
  const int wm = w >> 2, wn = w & 3;
  const int bm = blockIdx.y * 256, bn = blockIdx.x * 256;
  const int kz = (EPI == 3) ? (blockIdx.z << 10) : 0;
  f32x4 acc[8][4] = {};

  // swizzled LDS read offsets for A (shorts, within one ring buffer)
  int offA[8];
#pragma unroll
  for (int i = 0; i < 8; i++) {
    int r = wm * 128 + i * 16 + lm;
    offA[i] = r * 32 + (((kg + r + (r >> 2)) & 3) << 3);
  }
  // B fragment base pointers: direct global->reg (no LDS for B)
  const unsigned short* gBf[4];
#pragma unroll
  for (int j = 0; j < 4; j++)
    gBf[j] = Bg + (size_t)(bn + wn * 64 + j * 16 + lm) * ldb + kz + kg * 8;

  // A staging: 2 gload_lds per tile; dest linear, source k-slot inverse-swizzled
  const unsigned short* gA[2];
  int ldsoff[2];
#pragma unroll
  for (int i = 0; i < 2; i++) {
    int r = i * 128 + w * 16 + (lane >> 2);
    int q = ((lane & 3) - r - (r >> 2)) & 3;
    gA[i] = Ag + (size_t)(bm + r) * lda + kz + q * 8;
    ldsoff[i] = i * 4096 + w * 512;
  }
  auto stageA = [&](int tt, int buf) {
#pragma unroll
    for (int i = 0; i < 2; i++)
      __builtin_amdgcn_global_load_lds(
          (__attribute__((address_space(1))) void*)(unsigned short*)(gA[i] + tt * 32),
          (__attribute__((address_space(3))) void*)(As + buf * 8192 + ldsoff[i]),
          16, 0, 0);
  };

  // prologue: stage A tiles 0 and 1; vmcnt(2) -> A(0) complete, A(1) in flight
  stageA(0, 0);
  stageA(1, 1);
  asm volatile("s_waitcnt vmcnt(2)" ::: "memory");
  __builtin_amdgcn_s_barrier();
  __builtin_amdgcn_sched_barrier(0);

  for (int t = 0; t < NT; ++t) {
    const unsigned short* Ab = As + (t & 3) * 8192;
    // ---- issue B(t) regs (oldest), stage A(t+2), read aF; wait; MFMA-A ----
    bf16x8 bF[4];
#pragma unroll
    for (int j = 0; j < 4; j++) bF[j] = *(const bf16x8*)(gBf[j] + t * 32);
    if (t + 2 < NT) stageA(t + 2, (t + 2) & 3);
    bf16x8 aF[4];
#pragma unroll
    for (int i = 0; i < 4; i++) aF[i] = *(const bf16x8*)(Ab + offA[i]);
    __builtin_amdgcn_s_barrier();
    // retire {A(t+1), B(t)}; keep A(t+2) (newest 2) in flight
    if (t < NT - 2) { asm volatile("s_waitcnt vmcnt(2)" ::: "memory"); }
    else            { asm volatile("s_waitcnt vmcnt(0)" ::: "memory"); }
    asm volatile("s_waitcnt lgkmcnt(0)" ::: "memory");
    __builtin_amdgcn_sched_barrier(0);
    __builtin_amdgcn_s_setprio(1);
#pragma unroll
    for (int i = 0; i < 4; i++)
#pragma unroll
      for (int j = 0; j < 4; j++)
        acc[i][j] = __builtin_amdgcn_mfma_f32_16x16x32_bf16(aF[i], bF[j], acc[i][j], 0, 0, 0);
    __builtin_amdgcn_s_setprio(0);
    __builtin_amdgcn_sched_barrier(0);
    __builtin_amdgcn_s_barrier();
    // ---- phase B: read aG; MFMA-B ----
    bf16x8 aG[4];
#pragma unroll
    for (int i = 0; i < 4; i++) aG[i] = *(const bf16x8*)(Ab + offA[4 + i]);
    asm volatile("s_waitcnt lgkmcnt(0)" ::: "memory");
    __builtin_amdgcn_sched_barrier(0);
    __builtin_amdgcn_s_setprio(1);
#pragma unroll
    for (int i = 0; i < 4; i++)
#pragma unroll
      for (int j = 0; j < 4; j++)
        acc[4 + i][j] = __builtin_amdgcn_mfma_f32_16x16x32_bf16(aG[i], bF[j], acc[4 + i][j], 0, 0, 0);
    __builtin_amdgcn_s_setprio(0);
    __builtin_amdgcn_sched_barrier(0);
    __builtin_amdgcn_s_barrier();
  }

  // C/D layout (m89): col = lane&15, row = (lane>>4)*4 + reg
#pragma unroll
  for (int i = 0; i < 8; i++) {
#pragma unroll
    for (int j = 0; j < 4; j++) {
      const int gcol = bn + wn * 64 + j * 16 + lm;
      const int grow0 = bm + wm * 128 + i * 16 + kg * 4;
      if (EPI == 0) {
        const int which = gcol >> 10;  // uniform per block (256 | 1024)
        unsigned short* dst = which == 0 ? t0 : (which == 1 ? t1 : t2);
        const float bv = bias[gcol];
        ushort4 pk;
        pk.x = f2bf(acc[i][j][0] + bv);
        pk.y = f2bf(acc[i][j][1] + bv);
        pk.z = f2bf(acc[i][j][2] + bv);
        pk.w = f2bf(acc[i][j][3] + bv);
        *(ushort4*)(dst + (size_t)(gcol & 1023) * ldT + grow0) = pk;
      } else if (EPI == 1) {
        const float bv = bias[gcol];
        const float4 l4 = *(const float4*)(lrp + grow0);
        const ushort4 v4 = *(const ushort4*)(vTin + (size_t)gcol * ldT + grow0);
        ushort4 o;
        o.x = f2bf(l4.x * (bf2f(v4.x) - (acc[i][j][0] + bv)));
        o.y = f2bf(l4.y * (bf2f(v4.y) - (acc[i][j][1] + bv)));
        o.z = f2bf(l4.z * (bf2f(v4.z) - (acc[i][j][2] + bv)));
        o.w = f2bf(l4.w * (bf2f(v4.w) - (acc[i][j][3] + bv)));
        *(ushort4*)(outT + (size_t)gcol * ldT + grow0) = o;
      } else if (EPI == 2) {
        const float bv = bias[gcol];
#pragma unroll
        for (int r = 0; r < 4; r++)
          Cf[(size_t)(grow0 + r) * 1024 + gcol] = acc[i][j][r] + bv;
      } else {
        float* dst = Cf + (size_t)blockIdx.z * (1024ull * 1024ull);
#pragma unroll
        for (int r = 0; r < 4; r++)
          dst[(size_t)(grow0 + r) * 1024 + gcol] = acc[i][j][r];
      }
    }
  }
}

// ---------------------------------------------------------------------------
// Old 128x128 MFMA GEMM — kept only for the nc>1 fallback delta GEMM.
// ---------------------------------------------------------------------------
template <int EPI>
__global__ __launch_bounds__(256) void mgemm(
    const unsigned short* __restrict__ Ag, const unsigned short* __restrict__ Bg,
    int lda, int ldb, int ksl, const float* __restrict__ bias,
    unsigned short* __restrict__ t0, unsigned short* __restrict__ t1,
    unsigned short* __restrict__ t2, float* __restrict__ Cf,
    const unsigned short* __restrict__ vTin, const float* __restrict__ lrp,
    unsigned short* __restrict__ outT, int ldT) {
  __shared__ unsigned short As[128 * 32];
  __shared__ unsigned short Bs[128 * 32];
  const int tid = threadIdx.x, lane = tid & 63, w = tid >> 6;
  const int lm = lane & 15, kg = lane >> 4;
  const int mh = (w >> 1) * 64, nh = (w & 1) * 64;
  const int bm = blockIdx.y * 128, bn = blockIdx.x * 128;
  const int kstart = blockIdx.z * ksl, kend = kstart + ksl;
  f32x4 acc[4][4] = {};

  int offA[4], offB[4];
#pragma unroll
  for (int i = 0; i < 4; i++) {
    int rA = mh + i * 16 + lm;
    offA[i] = rA * 32 + (((kg + rA + (rA >> 2)) & 3) << 3);
    int rB = nh + i * 16 + lm;
    offB[i] = rB * 32 + (((kg + rB + (rB >> 2)) & 3) << 3);
  }
  int rowS[2], kcS[2];
#pragma unroll
  for (int t = 0; t < 2; t++) {
    int c = (w * 2 + t) * 64 + lane;
    rowS[t] = c >> 2;
    kcS[t] = ((((c & 3) - rowS[t] - (rowS[t] >> 2)) & 3) << 3);
  }

  for (int k0 = kstart; k0 < kend; k0 += 32) {
#pragma unroll
    for (int t = 0; t < 2; t++) {
      __builtin_amdgcn_global_load_lds(
          (__attribute__((address_space(1))) void*)(unsigned short*)(
              Ag + (size_t)(bm + rowS[t]) * lda + k0 + kcS[t]),
          (__attribute__((address_space(3))) void*)(As + (w * 2 + t) * 512), 16, 0, 0);
      __builtin_amdgcn_global_load_lds(
          (__attribute__((address_space(1))) void*)(unsigned short*)(
              Bg + (size_t)(bn + rowS[t]) * ldb + k0 + kcS[t]),
          (__attribute__((address_space(3))) void*)(Bs + (w * 2 + t) * 512), 16, 0, 0);
    }
    __syncthreads();
    bf16x8 aF[4], bF[4];
#pragma unroll
    for (int i = 0; i < 4; i++) {
      aF[i] = *(const bf16x8*)(As + offA[i]);
      bF[i] = *(const bf16x8*)(Bs + offB[i]);
    }
#pragma unroll
    for (int i = 0; i < 4; i++)
#pragma unroll
      for (int j = 0; j < 4; j++)
        acc[i][j] = __builtin_amdgcn_mfma_f32_16x16x32_bf16(aF[i], bF[j], acc[i][j], 0, 0, 0);
    __syncthreads();
  }

#pragma unroll
  for (int i = 0; i < 4; i++) {
#pragma unroll
    for (int j = 0; j < 4; j++) {
      const int gcol = bn + nh + j * 16 + lm;
      const int grow0 = bm + mh + i * 16 + kg * 4;
      if (EPI == 3) {
        float* dst = Cf + (size_t)blockIdx.z * (1024ull * 1024ull);
#pragma unroll
        for (int r = 0; r < 4; r++)
          dst[(size_t)(grow0 + r) * 1024 + gcol] = acc[i][j][r];
      }
    }
  }
}

// ---------------------------------------------------------------------------
// Transposed-input softmax (unchanged, r6)
// ---------------------------------------------------------------------------
template <bool DOSIG>
__global__ __launch_bounds__(256) void tsoftmax(
    const unsigned short* __restrict__ in, int ldin,
    unsigned short* __restrict__ rowout,
    unsigned short* __restrict__ sigT, int ldT) {
  __shared__ unsigned short tile[1024 * 16];
  __shared__ float red[16 * 17];
  const int t = threadIdx.x, bl = t & 15, fg = t >> 4;
  const int B0 = blockIdx.x * 16;
  const int f0 = fg * 64;
  float ls = 0.f;
  for (int f = f0; f < f0 + 64; f++) {
    unsigned short u = in[(size_t)f * ldin + B0 + bl];
    tile[f * 16 + bl] = u;
    ls += expf(bf2f(u));
  }
  red[bl * 17 + fg] = ls;
  __syncthreads();
  float tot = 0.f;
#pragma unroll
  for (int g = 0; g < 16; g++) tot += red[bl * 17 + g];
  const float inv = 1.0f / tot;
  for (int fb = f0; fb < f0 + 64; fb += 4) {
    float v[4];
#pragma unroll
    for (int e = 0; e < 4; e++) v[e] = bf2f(tile[(fb + e) * 16 + bl]);
    ushort4 o;
    o.x = f2bf(expf(v[0]) * inv);
    o.y = f2bf(expf(v[1]) * inv);
    o.z = f2bf(expf(v[2]) * inv);
    o.w = f2bf(expf(v[3]) * inv);
    *(ushort4*)(rowout + (size_t)(B0 + bl) * 1024 + fb) = o;
    if (DOSIG) {
#pragma unroll
      for (int e = 0; e < 4; e++)
        sigT[(size_t)(fb + e) * ldT + B0 + bl] = f2bf(sigm(v[e]));
    }
  }
}

__global__ __launch_bounds__(256) void lrx(const float* __restrict__ x,
                                           const float* __restrict__ Wsw,
                                           const float* __restrict__ Wsb,
                                           float* __restrict__ lrOut,
                                           unsigned short* __restrict__ xbf) {
  const int lane = threadIdx.x & 63, w = threadIdx.x >> 6;
  const int b = blockIdx.x * 4 + w;
  const float* xr = x + (size_t)b * 1024;
  const float* wr = Wsw + 3072ull * 1024ull;
  float sum = 0.f;
#pragma unroll
  for (int j = 0; j < 4; j++) {
    int f = lane + 64 * j;
    float4 xv = ((const float4*)xr)[f];
    float4 wv = ((const float4*)wr)[f];
    sum += xv.x * wv.x + xv.y * wv.y + xv.z * wv.z + xv.w * wv.w;
    ushort4 o = {f2bf(xv.x), f2bf(xv.y), f2bf(xv.z), f2bf(xv.w)};
    ((ushort4*)(xbf + (size_t)b * 1024))[f] = o;
  }
#pragma unroll
  for (int o = 32; o; o >>= 1) sum += __shfl_down(sum, o, 64);
  if (lane == 0) lrOut[b] = sigm(sum + Wsb[3072]);
}

__global__ __launch_bounds__(256) void cvt_bf(const float* __restrict__ in,
                                              unsigned short* __restrict__ outp) {
  size_t i = (size_t)blockIdx.x * 256 + threadIdx.x;
  float4 v = ((const float4*)in)[i];
  ushort4 o = {f2bf(v.x), f2bf(v.y), f2bf(v.z), f2bf(v.w)};
  ((ushort4*)outp)[i] = o;
}

// wnbf = bf16(Wfw + (sum of NZ P slices) / BATCH)
template <int NZ>
__global__ __launch_bounds__(256) void wnewk(const float* __restrict__ P,
                                             const float* __restrict__ Wfw,
                                             unsigned short* __restrict__ wnbf) {
  const size_t i = (size_t)blockIdx.x * 256 + threadIdx.x;
  float s = 0.f;
#pragma unroll
  for (int z = 0; z < NZ; z++) s += P[(size_t)z * (1024ull * 1024ull) + i];
  wnbf[i] = f2bf(Wfw[i] + s * (1.0f / 16384.0f));
}

extern "C" void kernel_launch(void* const* d_in, const int* in_sizes, int n_in,
                              void* d_out, int out_size, void* d_ws, size_t ws_size,
                              hipStream_t stream) {
  (void)in_sizes; (void)n_in; (void)out_size;
  const float* x   = (const float*)d_in[0];
  const float* Wsw = (const float*)d_in[1];
  const float* Wsb = (const float*)d_in[2];
  const float* Wfw = (const float*)d_in[3];
  const float* Wfb = (const float*)d_in[4];
  float* out = (float*)d_out;

  const size_t MB = 1ull << 20;
  int nc;
  if      (ws_size >= 216 * MB) nc = 1;
  else if (ws_size >= 164 * MB) nc = 2;
  else if (ws_size >= 122 * MB) nc = 4;
  else                          nc = 8;
  const size_t Bc = BATCH / nc;
  const int BcI = (int)Bc;
  const int zc = 8 / nc;
  const size_t CB = Bc * 1024 * 2;

  char* p = (char*)d_ws;
  size_t off = 0;
  auto alloc = [&](size_t bytes) {
    char* cur = p + off;
    off = (off + bytes + 255) & ~(size_t)255;
    return cur;
  };
  unsigned short* wbf  = (unsigned short*)alloc(3072ull * 1024 * 2);
  unsigned short* wfbf = (unsigned short*)alloc(1024ull * 1024 * 2);
  unsigned short* wnbf = (unsigned short*)alloc(1024ull * 1024 * 2);
  float*          lr   = (float*)alloc(BATCH * 4);
  unsigned short* qsm  = (unsigned short*)alloc((size_t)BATCH * 1024 * 2);

  unsigned short *xbf, *ksm, *kt, *Ut, *vT, *qt, *SKt;
  float* P;
  if (nc == 1) {
    char* rA = alloc(CB);  // xbf | ksm
    char* rB = alloc(CB);  // kt  | Ut
    char* rC = alloc(CB);  // vT  | P (slices 0-7)
    char* rD = alloc(CB);  // qt  | P (slices 8-15)   (rC,rD contiguous: CB is 256-aligned)
    char* rE = alloc(CB);  // SKt
    xbf = (unsigned short*)rA; ksm = (unsigned short*)rA;
    kt  = (unsigned short*)rB; Ut  = (unsigned short*)rB;
    vT  = (unsigned short*)rC;
    qt  = (unsigned short*)rD;
    P   = (float*)rC;      // 16 x 4MB = 64MB over rC..rD (vT,qt dead by then)
    SKt = (unsigned short*)rE;
  } else {
    P   = (float*)alloc(32 * MB);
    char* rA = alloc(CB);
    char* rB = alloc(CB);
    xbf = (unsigned short*)rA; ksm = (unsigned short*)rA;
    kt  = (unsigned short*)rB; Ut  = (unsigned short*)rB;
    vT  = (unsigned short*)alloc(CB);
    qt  = (unsigned short*)alloc(CB);
    SKt = (unsigned short*)alloc(CB);
  }

  cvt_bf<<<dim3(3072), 256, 0, stream>>>(Wsw, wbf);
  cvt_bf<<<dim3(1024), 256, 0, stream>>>(Wfw, wfbf);

  for (int c = 0; c < nc; c++) {
    const float* xc = x + (size_t)c * Bc * 1024;
    float* lrc = lr + (size_t)c * Bc;
    lrx<<<dim3((unsigned)(Bc / 4)), 256, 0, stream>>>(xc, Wsw, Wsb, lrc, xbf);
    // s = x @ Wslow^T + b  ->  kt | vT | qt   (all bf16 transposed [f][b])
    mgemm8<0><<<dim3(12, (unsigned)(Bc / 256)), 512, 0, stream>>>(
        xbf, wbf, 1024, 1024, Wsb, kt, vT, qt, nullptr, nullptr, nullptr,
        nullptr, BcI);
    // softmax(k) -> ksm [b][1024];  sigmoid(k)^T -> SKt [f][b]
    tsoftmax<true><<<dim3((unsigned)(Bc / 16)), 256, 0, stream>>>(
        kt, BcI, ksm, SKt, BcI);
    // softmax(q) -> qsm rows (persistent, row-major)
    tsoftmax<false><<<dim3((unsigned)(Bc / 16)), 256, 0, stream>>>(
        qt, BcI, qsm + (size_t)c * Bc * 1024, nullptr, BcI);
    // Ut[o][b] = bf16( lr * (v - (softmax(k) @ Wfw^T + Wfb)) )
    mgemm8<1><<<dim3(4, (unsigned)(Bc / 256)), 512, 0, stream>>>(
        ksm, wfbf, 1024, 1024, Wfb, nullptr, nullptr, nullptr, nullptr,
        vT, lrc, Ut, BcI);
    if (nc == 1) {
      // P[z] = Ut @ SKt^T over K-slice z*1024 (16 slices, 256 blocks = 1 round)
      mgemm8<3><<<dim3(4, 4, 16), 512, 0, stream>>>(
          Ut, SKt, BcI, BcI, nullptr, nullptr, nullptr, nullptr,
          P, nullptr, nullptr, nullptr, BcI);
    } else {
      mgemm<3><<<dim3(8, 8, zc), 256, 0, stream>>>(
          Ut, SKt, BcI, BcI, 2048, nullptr, nullptr, nullptr, nullptr,
          P + (size_t)c * zc * 1024 * 1024, nullptr, nullptr, nullptr, BcI);
    }
  }

  if (nc == 1)
    wnewk<16><<<dim3(1024 * 1024 / 256), 256, 0, stream>>>(P, Wfw, wnbf);
  else
    wnewk<8><<<dim3(1024 * 1024 / 256), 256, 0, stream>>>(P, Wfw, wnbf);

  // out = softmax(q) @ Wnew^T + Wfb   (fp32 row-major)
  mgemm8<2><<<dim3(4, BATCH / 256), 512, 0, stream>>>(
      qsm, wnbf, 1024, 1024, Wfb, nullptr, nullptr, nullptr, out,
      nullptr, nullptr, nullptr, 0);
}

// Round 9
// 624.162 us; speedup vs baseline: 1.0408x; 1.0408x over previous
//
#include <hip/hip_runtime.h>
#include <math.h>

static constexpr int BATCH = 16384;

typedef __attribute__((ext_vector_type(8))) __bf16 bf16x8;
typedef __attribute__((ext_vector_type(4))) float f32x4;

__device__ __forceinline__ float sigm(float x) { return 1.0f / (1.0f + expf(-x)); }

__device__ __forceinline__ unsigned short f2bf(float f) {
  unsigned u = __float_as_uint(f);
  return (unsigned short)((u + 0x7fffu + ((u >> 16) & 1u)) >> 16);
}
__device__ __forceinline__ float bf2f(unsigned short u) {
  return __uint_as_float((unsigned)u << 16);
}

// ---------------------------------------------------------------------------
// mgemm8: 256x256 tile, BK=32, K-span 1024 (NT=32), 8 waves (2M x 4N),
// per-wave 128x64 output (acc[8][4]). A: 4-deep LDS ring (64 KiB).
// B: direct global->reg with ONE-TILE-AHEAD ping-pong prefetch (bP/bQ,
// loop unrolled x2, static indexing). r8 proved B-direct cuts LDS bank
// conflicts 9.4M->6.3M but exposed L2 latency (B issued+consumed same
// tile); here B(t+1) is issued at tile-t top and consumed ~900 cyc later.
// r6 3-barrier sync skeleton unchanged.
// vmcnt ledger (in-order retire; per-tile issue order = B(t+1)x4 then
// stageA(t+2)x2): pre-MFMA-A retires B(t) -> vmcnt(8); boundary retires
// A(t+1) -> vmcnt(6). Tails t=NT-2: 6/4; t=NT-1: 0/0. Prologue vmcnt(2)
// retires {B(0), A(0)}, keeps A(1) in flight. Never 0 in steady state.
// HISTORY (do not re-try): r4 single-barrier merge = slower; r5 XCD
// swizzle = slower; r7 reads-up-front+lgkm(4) = slower; r8 B-direct
// without prefetch = much slower (latency exposure).
// EPI 0: bf16 transposed outputs (+bias) -> t0/t1/t2 [f][b]
// EPI 1: outT[gcol][grow..] = bf16( lr * (vTin - (acc+bias)) )
// EPI 2: Cf[grow][gcol] = acc + bias  (fp32 row-major)
// EPI 3: Cf + z*1M : [grow][gcol] = acc  (fp32 P slice, kz = z*1024)
// ---------------------------------------------------------------------------
template <int EPI>
__global__ __launch_bounds__(512, 2) void mgemm8(
    const unsigned short* __restrict__ Ag, const unsigned short* __restrict__ Bg,
    int lda, int ldb, const float* __restrict__ bias,
    unsigned short* __restrict__ t0, unsigned short* __restrict__ t1,
    unsigned short* __restrict__ t2, float* __restrict__ Cf,
    const unsigned short* __restrict__ vTin, const float* __restrict__ lrp,
    unsigned short* __restrict__ outT, int ldT) {
  constexpr int NT = 32;  // K-span 1024 / BK 32
  __shared__ unsigned short As[4 * 8192];  // 4-ring x 256x32 bf16, A only (64 KiB)
  const int tid = threadIdx.x, lane = tid & 63, w = tid >> 6;
  const int lm = lane & 15, kg = lane >> 4;
  const int wm = w >> 2, wn = w & 3;
  const int bm = blockIdx.y * 256, bn = blockIdx.x * 256;
  const int kz = (EPI == 3) ? (blockIdx.z << 10) : 0;
  f32x4 acc[8][4] = {};

  // swizzled LDS read offsets for A (shorts, within one ring buffer)
  int offA[8];
#pragma unroll
  for (int i = 0; i < 8; i++) {
    int r = wm * 128 + i * 16 + lm;
    offA[i] = r * 32 + (((kg + r + (r >> 2)) & 3) << 3);
  }
  // B fragment base pointers: direct global->reg (no LDS for B)
  const unsigned short* gBf[4];
#pragma unroll
  for (int j = 0; j < 4; j++)
    gBf[j] = Bg + (size_t)(bn + wn * 64 + j * 16 + lm) * ldb + kz + kg * 8;

  // A staging: 2 gload_lds per tile; dest linear, source k-slot inverse-swizzled
  const unsigned short* gA[2];
  int ldsoff[2];
#pragma unroll
  for (int i = 0; i < 2; i++) {
    int r = i * 128 + w * 16 + (lane >> 2);
    int q = ((lane & 3) - r - (r >> 2)) & 3;
    gA[i] = Ag + (size_t)(bm + r) * lda + kz + q * 8;
    ldsoff[i] = i * 4096 + w * 512;
  }
  auto stageA = [&](int tt, int buf) {
#pragma unroll
    for (int i = 0; i < 2; i++)
      __builtin_amdgcn_global_load_lds(
          (__attribute__((address_space(1))) void*)(unsigned short*)(gA[i] + tt * 32),
          (__attribute__((address_space(3))) void*)(As + buf * 8192 + ldsoff[i]),
          16, 0, 0);
  };

  bf16x8 bP[4], bQ[4];  // ping-pong B fragment sets (static indexing only)

  // prologue: B(0)->bP, stage A(0), A(1); vmcnt(2) retires {B(0), A(0)}
#pragma unroll
  for (int j = 0; j < 4; j++) bP[j] = *(const bf16x8*)(gBf[j]);
  stageA(0, 0);
  stageA(1, 1);
  asm volatile("s_waitcnt vmcnt(2)" ::: "memory");
  __builtin_amdgcn_s_barrier();
  __builtin_amdgcn_sched_barrier(0);

  auto body = [&](int t, bf16x8 (&bC)[4], bf16x8 (&bN)[4]) {
    const unsigned short* Ab = As + (t & 3) * 8192;
    // ---- phase A top: prefetch B(t+1)->bN, stage A(t+2), read aF ----
    if (t + 1 < NT) {
#pragma unroll
      for (int j = 0; j < 4; j++) bN[j] = *(const bf16x8*)(gBf[j] + (t + 1) * 32);
    }
    if (t + 2 < NT) stageA(t + 2, (t + 2) & 3);
    bf16x8 aF[4];
#pragma unroll
    for (int i = 0; i < 4; i++) aF[i] = *(const bf16x8*)(Ab + offA[i]);
    __builtin_amdgcn_s_barrier();
    // retire B(t); keep {A(t+1), B(t+1), A(t+2)} in flight
    if (t < NT - 2)       { asm volatile("s_waitcnt vmcnt(8)" ::: "memory"); }
    else if (t == NT - 2) { asm volatile("s_waitcnt vmcnt(6)" ::: "memory"); }
    else                  { asm volatile("s_waitcnt vmcnt(0)" ::: "memory"); }
    asm volatile("s_waitcnt lgkmcnt(0)" ::: "memory");
    __builtin_amdgcn_sched_barrier(0);
    __builtin_amdgcn_s_setprio(1);
#pragma unroll
    for (int i = 0; i < 4; i++)
#pragma unroll
      for (int j = 0; j < 4; j++)
        acc[i][j] = __builtin_amdgcn_mfma_f32_16x16x32_bf16(aF[i], bC[j], acc[i][j], 0, 0, 0);
    __builtin_amdgcn_s_setprio(0);
    __builtin_amdgcn_sched_barrier(0);
    __builtin_amdgcn_s_barrier();
    // ---- phase B: read aG; MFMA-B ----
    bf16x8 aG[4];
#pragma unroll
    for (int i = 0; i < 4; i++) aG[i] = *(const bf16x8*)(Ab + offA[4 + i]);
    asm volatile("s_waitcnt lgkmcnt(0)" ::: "memory");
    __builtin_amdgcn_sched_barrier(0);
    __builtin_amdgcn_s_setprio(1);
#pragma unroll
    for (int i = 0; i < 4; i++)
#pragma unroll
      for (int j = 0; j < 4; j++)
        acc[4 + i][j] = __builtin_amdgcn_mfma_f32_16x16x32_bf16(aG[i], bC[j], acc[4 + i][j], 0, 0, 0);
    __builtin_amdgcn_s_setprio(0);
    __builtin_amdgcn_sched_barrier(0);
    // boundary: retire A(t+1); keep {B(t+1), A(t+2)} in flight
    if (t < NT - 2)       { asm volatile("s_waitcnt vmcnt(6)" ::: "memory"); }
    else if (t == NT - 2) { asm volatile("s_waitcnt vmcnt(4)" ::: "memory"); }
    else                  { asm volatile("s_waitcnt vmcnt(0)" ::: "memory"); }
    __builtin_amdgcn_s_barrier();
    __builtin_amdgcn_sched_barrier(0);
  };

  for (int t = 0; t < NT; t += 2) {
    body(t, bP, bQ);
    body(t + 1, bQ, bP);
  }

  // C/D layout (m89): col = lane&15, row = (lane>>4)*4 + reg
#pragma unroll
  for (int i = 0; i < 8; i++) {
#pragma unroll
    for (int j = 0; j < 4; j++) {
      const int gcol = bn + wn * 64 + j * 16 + lm;
      const int grow0 = bm + wm * 128 + i * 16 + kg * 4;
      if (EPI == 0) {
        const int which = gcol >> 10;  // uniform per block (256 | 1024)
        unsigned short* dst = which == 0 ? t0 : (which == 1 ? t1 : t2);
        const float bv = bias[gcol];
        ushort4 pk;
        pk.x = f2bf(acc[i][j][0] + bv);
        pk.y = f2bf(acc[i][j][1] + bv);
        pk.z = f2bf(acc[i][j][2] + bv);
        pk.w = f2bf(acc[i][j][3] + bv);
        *(ushort4*)(dst + (size_t)(gcol & 1023) * ldT + grow0) = pk;
      } else if (EPI == 1) {
        const float bv = bias[gcol];
        const float4 l4 = *(const float4*)(lrp + grow0);
        const ushort4 v4 = *(const ushort4*)(vTin + (size_t)gcol * ldT + grow0);
        ushort4 o;
        o.x = f2bf(l4.x * (bf2f(v4.x) - (acc[i][j][0] + bv)));
        o.y = f2bf(l4.y * (bf2f(v4.y) - (acc[i][j][1] + bv)));
        o.z = f2bf(l4.z * (bf2f(v4.z) - (acc[i][j][2] + bv)));
        o.w = f2bf(l4.w * (bf2f(v4.w) - (acc[i][j][3] + bv)));
        *(ushort4*)(outT + (size_t)gcol * ldT + grow0) = o;
      } else if (EPI == 2) {
        const float bv = bias[gcol];
#pragma unroll
        for (int r = 0; r < 4; r++)
          Cf[(size_t)(grow0 + r) * 1024 + gcol] = acc[i][j][r] + bv;
      } else {
        float* dst = Cf + (size_t)blockIdx.z * (1024ull * 1024ull);
#pragma unroll
        for (int r = 0; r < 4; r++)
          dst[(size_t)(grow0 + r) * 1024 + gcol] = acc[i][j][r];
      }
    }
  }
}

// ---------------------------------------------------------------------------
// Old 128x128 MFMA GEMM — kept only for the nc>1 fallback delta GEMM.
// ---------------------------------------------------------------------------
template <int EPI>
__global__ __launch_bounds__(256) void mgemm(
    const unsigned short* __restrict__ Ag, const unsigned short* __restrict__ Bg,
    int lda, int ldb, int ksl, const float* __restrict__ bias,
    unsigned short* __restrict__ t0, unsigned short* __restrict__ t1,
    unsigned short* __restrict__ t2, float* __restrict__ Cf,
    const unsigned short* __restrict__ vTin, const float* __restrict__ lrp,
    unsigned short* __restrict__ outT, int ldT) {
  __shared__ unsigned short As[128 * 32];
  __shared__ unsigned short Bs[128 * 32];
  const int tid = threadIdx.x, lane = tid & 63, w = tid >> 6;
  const int lm = lane & 15, kg = lane >> 4;
  const int mh = (w >> 1) * 64, nh = (w & 1) * 64;
  const int bm = blockIdx.y * 128, bn = blockIdx.x * 128;
  const int kstart = blockIdx.z * ksl, kend = kstart + ksl;
  f32x4 acc[4][4] = {};

  int offA[4], offB[4];
#pragma unroll
  for (int i = 0; i < 4; i++) {
    int rA = mh + i * 16 + lm;
    offA[i] = rA * 32 + (((kg + rA + (rA >> 2)) & 3) << 3);
    int rB = nh + i * 16 + lm;
    offB[i] = rB * 32 + (((kg + rB + (rB >> 2)) & 3) << 3);
  }
  int rowS[2], kcS[2];
#pragma unroll
  for (int t = 0; t < 2; t++) {
    int c = (w * 2 + t) * 64 + lane;
    rowS[t] = c >> 2;
    kcS[t] = ((((c & 3) - rowS[t] - (rowS[t] >> 2)) & 3) << 3);
  }

  for (int k0 = kstart; k0 < kend; k0 += 32) {
#pragma unroll
    for (int t = 0; t < 2; t++) {
      __builtin_amdgcn_global_load_lds(
          (__attribute__((address_space(1))) void*)(unsigned short*)(
              Ag + (size_t)(bm + rowS[t]) * lda + k0 + kcS[t]),
          (__attribute__((address_space(3))) void*)(As + (w * 2 + t) * 512), 16, 0, 0);
      __builtin_amdgcn_global_load_lds(
          (__attribute__((address_space(1))) void*)(unsigned short*)(
              Bg + (size_t)(bn + rowS[t]) * ldb + k0 + kcS[t]),
          (__attribute__((address_space(3))) void*)(Bs + (w * 2 + t) * 512), 16, 0, 0);
    }
    __syncthreads();
    bf16x8 aF[4], bF[4];
#pragma unroll
    for (int i = 0; i < 4; i++) {
      aF[i] = *(const bf16x8*)(As + offA[i]);
      bF[i] = *(const bf16x8*)(Bs + offB[i]);
    }
#pragma unroll
    for (int i = 0; i < 4; i++)
#pragma unroll
      for (int j = 0; j < 4; j++)
        acc[i][j] = __builtin_amdgcn_mfma_f32_16x16x32_bf16(aF[i], bF[j], acc[i][j], 0, 0, 0);
    __syncthreads();
  }

#pragma unroll
  for (int i = 0; i < 4; i++) {
#pragma unroll
    for (int j = 0; j < 4; j++) {
      const int gcol = bn + nh + j * 16 + lm;
      const int grow0 = bm + mh + i * 16 + kg * 4;
      if (EPI == 3) {
        float* dst = Cf + (size_t)blockIdx.z * (1024ull * 1024ull);
#pragma unroll
        for (int r = 0; r < 4; r++)
          dst[(size_t)(grow0 + r) * 1024 + gcol] = acc[i][j][r];
      }
    }
  }
}

// ---------------------------------------------------------------------------
// Transposed-input softmax (unchanged, r6)
// ---------------------------------------------------------------------------
template <bool DOSIG>
__global__ __launch_bounds__(256) void tsoftmax(
    const unsigned short* __restrict__ in, int ldin,
    unsigned short* __restrict__ rowout,
    unsigned short* __restrict__ sigT, int ldT) {
  __shared__ unsigned short tile[1024 * 16];
  __shared__ float red[16 * 17];
  const int t = threadIdx.x, bl = t & 15, fg = t >> 4;
  const int B0 = blockIdx.x * 16;
  const int f0 = fg * 64;
  float ls = 0.f;
  for (int f = f0; f < f0 + 64; f++) {
    unsigned short u = in[(size_t)f * ldin + B0 + bl];
    tile[f * 16 + bl] = u;
    ls += expf(bf2f(u));
  }
  red[bl * 17 + fg] = ls;
  __syncthreads();
  float tot = 0.f;
#pragma unroll
  for (int g = 0; g < 16; g++) tot += red[bl * 17 + g];
  const float inv = 1.0f / tot;
  for (int fb = f0; fb < f0 + 64; fb += 4) {
    float v[4];
#pragma unroll
    for (int e = 0; e < 4; e++) v[e] = bf2f(tile[(fb + e) * 16 + bl]);
    ushort4 o;
    o.x = f2bf(expf(v[0]) * inv);
    o.y = f2bf(expf(v[1]) * inv);
    o.z = f2bf(expf(v[2]) * inv);
    o.w = f2bf(expf(v[3]) * inv);
    *(ushort4*)(rowout + (size_t)(B0 + bl) * 1024 + fb) = o;
    if (DOSIG) {
#pragma unroll
      for (int e = 0; e < 4; e++)
        sigT[(size_t)(fb + e) * ldT + B0 + bl] = f2bf(sigm(v[e]));
    }
  }
}

__global__ __launch_bounds__(256) void lrx(const float* __restrict__ x,
                                           const float* __restrict__ Wsw,
                                           const float* __restrict__ Wsb,
                                           float* __restrict__ lrOut,
                                           unsigned short* __restrict__ xbf) {
  const int lane = threadIdx.x & 63, w = threadIdx.x >> 6;
  const int b = blockIdx.x * 4 + w;
  const float* xr = x + (size_t)b * 1024;
  const float* wr = Wsw + 3072ull * 1024ull;
  float sum = 0.f;
#pragma unroll
  for (int j = 0; j < 4; j++) {
    int f = lane + 64 * j;
    float4 xv = ((const float4*)xr)[f];
    float4 wv = ((const float4*)wr)[f];
    sum += xv.x * wv.x + xv.y * wv.y + xv.z * wv.z + xv.w * wv.w;
    ushort4 o = {f2bf(xv.x), f2bf(xv.y), f2bf(xv.z), f2bf(xv.w)};
    ((ushort4*)(xbf + (size_t)b * 1024))[f] = o;
  }
#pragma unroll
  for (int o = 32; o; o >>= 1) sum += __shfl_down(sum, o, 64);
  if (lane == 0) lrOut[b] = sigm(sum + Wsb[3072]);
}

__global__ __launch_bounds__(256) void cvt_bf(const float* __restrict__ in,
                                              unsigned short* __restrict__ outp) {
  size_t i = (size_t)blockIdx.x * 256 + threadIdx.x;
  float4 v = ((const float4*)in)[i];
  ushort4 o = {f2bf(v.x), f2bf(v.y), f2bf(v.z), f2bf(v.w)};
  ((ushort4*)outp)[i] = o;
}

// wnbf = bf16(Wfw + (sum of NZ P slices) / BATCH)
template <int NZ>
__global__ __launch_bounds__(256) void wnewk(const float* __restrict__ P,
                                             const float* __restrict__ Wfw,
                                             unsigned short* __restrict__ wnbf) {
  const size_t i = (size_t)blockIdx.x * 256 + threadIdx.x;
  float s = 0.f;
#pragma unroll
  for (int z = 0; z < NZ; z++) s += P[(size_t)z * (1024ull * 1024ull) + i];
  wnbf[i] = f2bf(Wfw[i] + s * (1.0f / 16384.0f));
}

extern "C" void kernel_launch(void* const* d_in, const int* in_sizes, int n_in,
                              void* d_out, int out_size, void* d_ws, size_t ws_size,
                              hipStream_t stream) {
  (void)in_sizes; (void)n_in; (void)out_size;
  const float* x   = (const float*)d_in[0];
  const float* Wsw = (const float*)d_in[1];
  const float* Wsb = (const float*)d_in[2];
  const float* Wfw = (const float*)d_in[3];
  const float* Wfb = (const float*)d_in[4];
  float* out = (float*)d_out;

  const size_t MB = 1ull << 20;
  int nc;
  if      (ws_size >= 216 * MB) nc = 1;
  else if (ws_size >= 164 * MB) nc = 2;
  else if (ws_size >= 122 * MB) nc = 4;
  else                          nc = 8;
  const size_t Bc = BATCH / nc;
  const int BcI = (int)Bc;
  const int zc = 8 / nc;
  const size_t CB = Bc * 1024 * 2;

  char* p = (char*)d_ws;
  size_t off = 0;
  auto alloc = [&](size_t bytes) {
    char* cur = p + off;
    off = (off + bytes + 255) & ~(size_t)255;
    return cur;
  };
  unsigned short* wbf  = (unsigned short*)alloc(3072ull * 1024 * 2);
  unsigned short* wfbf = (unsigned short*)alloc(1024ull * 1024 * 2);
  unsigned short* wnbf = (unsigned short*)alloc(1024ull * 1024 * 2);
  float*          lr   = (float*)alloc(BATCH * 4);
  unsigned short* qsm  = (unsigned short*)alloc((size_t)BATCH * 1024 * 2);

  unsigned short *xbf, *ksm, *kt, *Ut, *vT, *qt, *SKt;
  float* P;
  if (nc == 1) {
    char* rA = alloc(CB);  // xbf | ksm
    char* rB = alloc(CB);  // kt  | Ut
    char* rC = alloc(CB);  // vT  | P (slices 0-7)
    char* rD = alloc(CB);  // qt  | P (slices 8-15)   (rC,rD contiguous: CB is 256-aligned)
    char* rE = alloc(CB);  // SKt
    xbf = (unsigned short*)rA; ksm = (unsigned short*)rA;
    kt  = (unsigned short*)rB; Ut  = (unsigned short*)rB;
    vT  = (unsigned short*)rC;
    qt  = (unsigned short*)rD;
    P   = (float*)rC;      // 16 x 4MB = 64MB over rC..rD (vT,qt dead by then)
    SKt = (unsigned short*)rE;
  } else {
    P   = (float*)alloc(32 * MB);
    char* rA = alloc(CB);
    char* rB = alloc(CB);
    xbf = (unsigned short*)rA; ksm = (unsigned short*)rA;
    kt  = (unsigned short*)rB; Ut  = (unsigned short*)rB;
    vT  = (unsigned short*)alloc(CB);
    qt  = (unsigned short*)alloc(CB);
    SKt = (unsigned short*)alloc(CB);
  }

  cvt_bf<<<dim3(3072), 256, 0, stream>>>(Wsw, wbf);
  cvt_bf<<<dim3(1024), 256, 0, stream>>>(Wfw, wfbf);

  for (int c = 0; c < nc; c++) {
    const float* xc = x + (size_t)c * Bc * 1024;
    float* lrc = lr + (size_t)c * Bc;
    lrx<<<dim3((unsigned)(Bc / 4)), 256, 0, stream>>>(xc, Wsw, Wsb, lrc, xbf);
    // s = x @ Wslow^T + b  ->  kt | vT | qt   (all bf16 transposed [f][b])
    mgemm8<0><<<dim3(12, (unsigned)(Bc / 256)), 512, 0, stream>>>(
        xbf, wbf, 1024, 1024, Wsb, kt, vT, qt, nullptr, nullptr, nullptr,
        nullptr, BcI);
    // softmax(k) -> ksm [b][1024];  sigmoid(k)^T -> SKt [f][b]
    tsoftmax<true><<<dim3((unsigned)(Bc / 16)), 256, 0, stream>>>(
        kt, BcI, ksm, SKt, BcI);
    // softmax(q) -> qsm rows (persistent, row-major)
    tsoftmax<false><<<dim3((unsigned)(Bc / 16)), 256, 0, stream>>>(
        qt, BcI, qsm + (size_t)c * Bc * 1024, nullptr, BcI);
    // Ut[o][b] = bf16( lr * (v - (softmax(k) @ Wfw^T + Wfb)) )
    mgemm8<1><<<dim3(4, (unsigned)(Bc / 256)), 512, 0, stream>>>(
        ksm, wfbf, 1024, 1024, Wfb, nullptr, nullptr, nullptr, nullptr,
        vT, lrc, Ut, BcI);
    if (nc == 1) {
      // P[z] = Ut @ SKt^T over K-slice z*1024 (16 slices, 256 blocks = 1 round)
      mgemm8<3><<<dim3(4, 4, 16), 512, 0, stream>>>(
          Ut, SKt, BcI, BcI, nullptr, nullptr, nullptr, nullptr,
          P, nullptr, nullptr, nullptr, BcI);
    } else {
      mgemm<3><<<dim3(8, 8, zc), 256, 0, stream>>>(
          Ut, SKt, BcI, BcI, 2048, nullptr, nullptr, nullptr, nullptr,
          P + (size_t)c * zc * 1024 * 1024, nullptr, nullptr, nullptr, BcI);
    }
  }

  if (nc == 1)
    wnewk<16><<<dim3(1024 * 1024 / 256), 256, 0, stream>>>(P, Wfw, wnbf);
  else
    wnewk<8><<<dim3(1024 * 1024 / 256), 256, 0, stream>>>(P, Wfw, wnbf);

  // out = softmax(q) @ Wnew^T + Wfb   (fp32 row-major)
  mgemm8<2><<<dim3(4, BATCH / 256), 512, 0, stream>>>(
      qsm, wnbf, 1024, 1024, Wfb, nullptr, nullptr, nullptr, out,
      nullptr, nullptr, nullptr, 0);
}

// Round 10
// 502.685 us; speedup vs baseline: 1.2923x; 1.2417x over previous
//
#include <hip/hip_runtime.h>
#include <math.h>

static constexpr int BATCH = 16384;

typedef __attribute__((ext_vector_type(8))) __bf16 bf16x8;
typedef __attribute__((ext_vector_type(4))) float f32x4;

__device__ __forceinline__ float sigm(float x) { return 1.0f / (1.0f + expf(-x)); }

__device__ __forceinline__ unsigned short f2bf(float f) {
  unsigned u = __float_as_uint(f);
  return (unsigned short)((u + 0x7fffu + ((u >> 16) & 1u)) >> 16);
}
__device__ __forceinline__ float bf2f(unsigned short u) {
  return __uint_as_float((unsigned)u << 16);
}

// ---------------------------------------------------------------------------
// mgemm8: 256x256 tile, BK=32, K-span = 1024 (NT=32), 8 waves (2M x 4N),
// per-wave 128x64 output (acc[8][4]). 4-deep LDS ring (128 KiB).
// ROUND-3/6 VERIFIED SCHEDULE (4 barriers/tile, counted vmcnt(4) at tile
// boundary — never 0 in steady state; lgkmcnt(0)+sched_barrier guarding
// each MFMA cluster; setprio(1) around MFMA).  THIS IS THE ANCHOR (133 µs
// for EPI 0, 506 µs total).
// HISTORY (do not re-try): r4 single-barrier merge = 160 µs; r5 XCD block
// swizzle = 167 µs + write amplification; r7 reads-up-front + lgkm(4) =
// 140 µs; r8 B-direct-to-regs = 208 µs (L2 address-divergence); r9
// B-direct + 1-tile prefetch = 194 µs (same limit).
// EPI 3: per-block K-offset kz = blockIdx.z*1024 (delta GEMM, 16 K-slices).
// LDS slots source-swizzled (slot = (kg + r + r>>2) & 3).
// EPI 0: bf16 transposed outputs (+bias) -> t0/t1/t2 [f][b]
// EPI 1: outT[gcol][grow..] = bf16( lr * (vTin - (acc+bias)) )
// EPI 2: Cf[grow][gcol] = acc + bias  (fp32 row-major)
// EPI 3: Cf + z*1M : [grow][gcol] = acc  (fp32 P slice, no bias)
// ---------------------------------------------------------------------------
template <int EPI>
__global__ __launch_bounds__(512, 2) void mgemm8(
    const unsigned short* __restrict__ Ag, const unsigned short* __restrict__ Bg,
    int lda, int ldb, const float* __restrict__ bias,
    unsigned short* __restrict__ t0, unsigned short* __restrict__ t1,
    unsigned short* __restrict__ t2, float* __restrict__ Cf,
    const unsigned short* __restrict__ vTin, const float* __restrict__ lrp,
    unsigned short* __restrict__ outT, int ldT) {
  constexpr int NT = 32;  // K-span 1024 / BK 32
  __shared__ unsigned short As[4 * 8192];  // 4 ring buffers x 256x32 bf16
  __shared__ unsigned short Bs[4 * 8192];
  const int tid = threadIdx.x, lane = tid & 63, w = tid >> 6;
  const int lm = lane & 15, kg = lane >> 4;
  const int wm = w >> 2, wn = w & 3;
  const int bm = blockIdx.y * 256, bn = blockIdx.x * 256;
  const int kz = (EPI == 3) ? (blockIdx.z << 10) : 0;
  f32x4 acc[8][4] = {};

  // swizzled LDS read offsets (shorts, within one ring buffer)
  int offA[8], offB[4];
#pragma unroll
  for (int i = 0; i < 8; i++) {
    int r = wm * 128 + i * 16 + lm;
    offA[i] = r * 32 + (((kg + r + (r >> 2)) & 3) << 3);
  }
#pragma unroll
  for (int j = 0; j < 4; j++) {
    int r = wn * 64 + j * 16 + lm;
    offB[j] = r * 32 + (((kg + r + (r >> 2)) & 3) << 3);
  }
  // staging: 2 insts per matrix per tile; dest is linear (wave base + lane*16),
  // source k-slot inverse-swizzled so reads see logical k-groups.
  const unsigned short* gA[2];
  const unsigned short* gB[2];
  int ldsoff[2];
#pragma unroll
  for (int i = 0; i < 2; i++) {
    int r = i * 128 + w * 16 + (lane >> 2);
    int q = ((lane & 3) - r - (r >> 2)) & 3;
    gA[i] = Ag + (size_t)(bm + r) * lda + kz + q * 8;
    gB[i] = Bg + (size_t)(bn + r) * ldb + kz + q * 8;
    ldsoff[i] = i * 4096 + w * 512;
  }
  auto stageA = [&](int tt, int buf) {
#pragma unroll
    for (int i = 0; i < 2; i++)
      __builtin_amdgcn_global_load_lds(
          (__attribute__((address_space(1))) void*)(unsigned short*)(gA[i] + tt * 32),
          (__attribute__((address_space(3))) void*)(As + buf * 8192 + ldsoff[i]),
          16, 0, 0);
  };
  auto stageB = [&](int tt, int buf) {
#pragma unroll
    for (int i = 0; i < 2; i++)
      __builtin_amdgcn_global_load_lds(
          (__attribute__((address_space(1))) void*)(unsigned short*)(gB[i] + tt * 32),
          (__attribute__((address_space(3))) void*)(Bs + buf * 8192 + ldsoff[i]),
          16, 0, 0);
  };

  // prologue: stage tiles 0 and 1 (8 insts); vmcnt(4) -> tile 0 complete
  stageA(0, 0); stageB(0, 0);
  stageA(1, 1); stageB(1, 1);
  asm volatile("s_waitcnt vmcnt(4)" ::: "memory");
  __builtin_amdgcn_s_barrier();
  __builtin_amdgcn_sched_barrier(0);

  for (int t = 0; t < NT; ++t) {
    const unsigned short* Ab = As + (t & 3) * 8192;
    const unsigned short* Bb = Bs + (t & 3) * 8192;
    // ---- phase A: 8 ds_reads, stage A(t+2), 16 MFMA (m0-3 x n0-3) ----
    bf16x8 aF[4], bF[4];
#pragma unroll
    for (int i = 0; i < 4; i++) aF[i] = *(const bf16x8*)(Ab + offA[i]);
#pragma unroll
    for (int j = 0; j < 4; j++) bF[j] = *(const bf16x8*)(Bb + offB[j]);
    if (t + 2 < NT) stageA(t + 2, (t + 2) & 3);
    __builtin_amdgcn_s_barrier();
    asm volatile("s_waitcnt lgkmcnt(0)" ::: "memory");
    __builtin_amdgcn_sched_barrier(0);
    __builtin_amdgcn_s_setprio(1);
#pragma unroll
    for (int i = 0; i < 4; i++)
#pragma unroll
      for (int j = 0; j < 4; j++)
        acc[i][j] = __builtin_amdgcn_mfma_f32_16x16x32_bf16(aF[i], bF[j], acc[i][j], 0, 0, 0);
    __builtin_amdgcn_s_setprio(0);
    __builtin_amdgcn_sched_barrier(0);
    __builtin_amdgcn_s_barrier();
    // ---- phase B: 4 ds_reads, stage B(t+2), 16 MFMA (m4-7 x n0-3) ----
    bf16x8 aG[4];
#pragma unroll
    for (int i = 0; i < 4; i++) aG[i] = *(const bf16x8*)(Ab + offA[4 + i]);
    if (t + 2 < NT) stageB(t + 2, (t + 2) & 3);
    __builtin_amdgcn_s_barrier();
    asm volatile("s_waitcnt lgkmcnt(0)" ::: "memory");
    __builtin_amdgcn_sched_barrier(0);
    __builtin_amdgcn_s_setprio(1);
#pragma unroll
    for (int i = 0; i < 4; i++)
#pragma unroll
      for (int j = 0; j < 4; j++)
        acc[4 + i][j] = __builtin_amdgcn_mfma_f32_16x16x32_bf16(aG[i], bF[j], acc[4 + i][j], 0, 0, 0);
    __builtin_amdgcn_s_setprio(0);
    __builtin_amdgcn_sched_barrier(0);
    // tile boundary: force tile t+1 complete, keep tile t+2 (newest 4) in flight
    if (t < NT - 2) { asm volatile("s_waitcnt vmcnt(4)" ::: "memory"); }
    else            { asm volatile("s_waitcnt vmcnt(0)" ::: "memory"); }
    __builtin_amdgcn_s_barrier();
    __builtin_amdgcn_sched_barrier(0);
  }

  // C/D layout (m89): col = lane&15, row = (lane>>4)*4 + reg
#pragma unroll
  for (int i = 0; i < 8; i++) {
#pragma unroll
    for (int j = 0; j < 4; j++) {
      const int gcol = bn + wn * 64 + j * 16 + lm;
      const int grow0 = bm + wm * 128 + i * 16 + kg * 4;
      if (EPI == 0) {
        const int which = gcol >> 10;  // uniform per block (256 | 1024)
        unsigned short* dst = which == 0 ? t0 : (which == 1 ? t1 : t2);
        const float bv = bias[gcol];
        ushort4 pk;
        pk.x = f2bf(acc[i][j][0] + bv);
        pk.y = f2bf(acc[i][j][1] + bv);
        pk.z = f2bf(acc[i][j][2] + bv);
        pk.w = f2bf(acc[i][j][3] + bv);
        *(ushort4*)(dst + (size_t)(gcol & 1023) * ldT + grow0) = pk;
      } else if (EPI == 1) {
        const float bv = bias[gcol];
        const float4 l4 = *(const float4*)(lrp + grow0);
        const ushort4 v4 = *(const ushort4*)(vTin + (size_t)gcol * ldT + grow0);
        ushort4 o;
        o.x = f2bf(l4.x * (bf2f(v4.x) - (acc[i][j][0] + bv)));
        o.y = f2bf(l4.y * (bf2f(v4.y) - (acc[i][j][1] + bv)));
        o.z = f2bf(l4.z * (bf2f(v4.z) - (acc[i][j][2] + bv)));
        o.w = f2bf(l4.w * (bf2f(v4.w) - (acc[i][j][3] + bv)));
        *(ushort4*)(outT + (size_t)gcol * ldT + grow0) = o;
      } else if (EPI == 2) {
        const float bv = bias[gcol];
#pragma unroll
        for (int r = 0; r < 4; r++)
          Cf[(size_t)(grow0 + r) * 1024 + gcol] = acc[i][j][r] + bv;
      } else {
        float* dst = Cf + (size_t)blockIdx.z * (1024ull * 1024ull);
#pragma unroll
        for (int r = 0; r < 4; r++)
          dst[(size_t)(grow0 + r) * 1024 + gcol] = acc[i][j][r];
      }
    }
  }
}

// ---------------------------------------------------------------------------
// Old 128x128 MFMA GEMM — kept only for the nc>1 fallback delta GEMM.
// ---------------------------------------------------------------------------
template <int EPI>
__global__ __launch_bounds__(256) void mgemm(
    const unsigned short* __restrict__ Ag, const unsigned short* __restrict__ Bg,
    int lda, int ldb, int ksl, const float* __restrict__ bias,
    unsigned short* __restrict__ t0, unsigned short* __restrict__ t1,
    unsigned short* __restrict__ t2, float* __restrict__ Cf,
    const unsigned short* __restrict__ vTin, const float* __restrict__ lrp,
    unsigned short* __restrict__ outT, int ldT) {
  __shared__ unsigned short As[128 * 32];
  __shared__ unsigned short Bs[128 * 32];
  const int tid = threadIdx.x, lane = tid & 63, w = tid >> 6;
  const int lm = lane & 15, kg = lane >> 4;
  const int mh = (w >> 1) * 64, nh = (w & 1) * 64;
  const int bm = blockIdx.y * 128, bn = blockIdx.x * 128;
  const int kstart = blockIdx.z * ksl, kend = kstart + ksl;
  f32x4 acc[4][4] = {};

  int offA[4], offB[4];
#pragma unroll
  for (int i = 0; i < 4; i++) {
    int rA = mh + i * 16 + lm;
    offA[i] = rA * 32 + (((kg + rA + (rA >> 2)) & 3) << 3);
    int rB = nh + i * 16 + lm;
    offB[i] = rB * 32 + (((kg + rB + (rB >> 2)) & 3) << 3);
  }
  int rowS[2], kcS[2];
#pragma unroll
  for (int t = 0; t < 2; t++) {
    int c = (w * 2 + t) * 64 + lane;
    rowS[t] = c >> 2;
    kcS[t] = ((((c & 3) - rowS[t] - (rowS[t] >> 2)) & 3) << 3);
  }

  for (int k0 = kstart; k0 < kend; k0 += 32) {
#pragma unroll
    for (int t = 0; t < 2; t++) {
      __builtin_amdgcn_global_load_lds(
          (__attribute__((address_space(1))) void*)(unsigned short*)(
              Ag + (size_t)(bm + rowS[t]) * lda + k0 + kcS[t]),
          (__attribute__((address_space(3))) void*)(As + (w * 2 + t) * 512), 16, 0, 0);
      __builtin_amdgcn_global_load_lds(
          (__attribute__((address_space(1))) void*)(unsigned short*)(
              Bg + (size_t)(bn + rowS[t]) * ldb + k0 + kcS[t]),
          (__attribute__((address_space(3))) void*)(Bs + (w * 2 + t) * 512), 16, 0, 0);
    }
    __syncthreads();
    bf16x8 aF[4], bF[4];
#pragma unroll
    for (int i = 0; i < 4; i++) {
      aF[i] = *(const bf16x8*)(As + offA[i]);
      bF[i] = *(const bf16x8*)(Bs + offB[i]);
    }
#pragma unroll
    for (int i = 0; i < 4; i++)
#pragma unroll
      for (int j = 0; j < 4; j++)
        acc[i][j] = __builtin_amdgcn_mfma_f32_16x16x32_bf16(aF[i], bF[j], acc[i][j], 0, 0, 0);
    __syncthreads();
  }

#pragma unroll
  for (int i = 0; i < 4; i++) {
#pragma unroll
    for (int j = 0; j < 4; j++) {
      const int gcol = bn + nh + j * 16 + lm;
      const int grow0 = bm + mh + i * 16 + kg * 4;
      if (EPI == 3) {
        float* dst = Cf + (size_t)blockIdx.z * (1024ull * 1024ull);
#pragma unroll
        for (int r = 0; r < 4; r++)
          dst[(size_t)(grow0 + r) * 1024 + gcol] = acc[i][j][r];
      }
    }
  }
}

// ---------------------------------------------------------------------------
// Transposed-input softmax (unchanged, r6)
// ---------------------------------------------------------------------------
template <bool DOSIG>
__global__ __launch_bounds__(256) void tsoftmax(
    const unsigned short* __restrict__ in, int ldin,
    unsigned short* __restrict__ rowout,
    unsigned short* __restrict__ sigT, int ldT) {
  __shared__ unsigned short tile[1024 * 16];
  __shared__ float red[16 * 17];
  const int t = threadIdx.x, bl = t & 15, fg = t >> 4;
  const int B0 = blockIdx.x * 16;
  const int f0 = fg * 64;
  float ls = 0.f;
  for (int f = f0; f < f0 + 64; f++) {
    unsigned short u = in[(size_t)f * ldin + B0 + bl];
    tile[f * 16 + bl] = u;
    ls += expf(bf2f(u));
  }
  red[bl * 17 + fg] = ls;
  __syncthreads();
  float tot = 0.f;
#pragma unroll
  for (int g = 0; g < 16; g++) tot += red[bl * 17 + g];
  const float inv = 1.0f / tot;
  for (int fb = f0; fb < f0 + 64; fb += 4) {
    float v[4];
#pragma unroll
    for (int e = 0; e < 4; e++) v[e] = bf2f(tile[(fb + e) * 16 + bl]);
    ushort4 o;
    o.x = f2bf(expf(v[0]) * inv);
    o.y = f2bf(expf(v[1]) * inv);
    o.z = f2bf(expf(v[2]) * inv);
    o.w = f2bf(expf(v[3]) * inv);
    *(ushort4*)(rowout + (size_t)(B0 + bl) * 1024 + fb) = o;
    if (DOSIG) {
#pragma unroll
      for (int e = 0; e < 4; e++)
        sigT[(size_t)(fb + e) * ldT + B0 + bl] = f2bf(sigm(v[e]));
    }
  }
}

__global__ __launch_bounds__(256) void lrx(const float* __restrict__ x,
                                           const float* __restrict__ Wsw,
                                           const float* __restrict__ Wsb,
                                           float* __restrict__ lrOut,
                                           unsigned short* __restrict__ xbf) {
  const int lane = threadIdx.x & 63, w = threadIdx.x >> 6;
  const int b = blockIdx.x * 4 + w;
  const float* xr = x + (size_t)b * 1024;
  const float* wr = Wsw + 3072ull * 1024ull;
  float sum = 0.f;
#pragma unroll
  for (int j = 0; j < 4; j++) {
    int f = lane + 64 * j;
    float4 xv = ((const float4*)xr)[f];
    float4 wv = ((const float4*)wr)[f];
    sum += xv.x * wv.x + xv.y * wv.y + xv.z * wv.z + xv.w * wv.w;
    ushort4 o = {f2bf(xv.x), f2bf(xv.y), f2bf(xv.z), f2bf(xv.w)};
    ((ushort4*)(xbf + (size_t)b * 1024))[f] = o;
  }
#pragma unroll
  for (int o = 32; o; o >>= 1) sum += __shfl_down(sum, o, 64);
  if (lane == 0) lrOut[b] = sigm(sum + Wsb[3072]);
}

__global__ __launch_bounds__(256) void cvt_bf(const float* __restrict__ in,
                                              unsigned short* __restrict__ outp) {
  size_t i = (size_t)blockIdx.x * 256 + threadIdx.x;
  float4 v = ((const float4*)in)[i];
  ushort4 o = {f2bf(v.x), f2bf(v.y), f2bf(v.z), f2bf(v.w)};
  ((ushort4*)outp)[i] = o;
}

// wnbf = bf16(Wfw + (sum of NZ P slices) / BATCH)
template <int NZ>
__global__ __launch_bounds__(256) void wnewk(const float* __restrict__ P,
                                             const float* __restrict__ Wfw,
                                             unsigned short* __restrict__ wnbf) {
  const size_t i = (size_t)blockIdx.x * 256 + threadIdx.x;
  float s = 0.f;
#pragma unroll
  for (int z = 0; z < NZ; z++) s += P[(size_t)z * (1024ull * 1024ull) + i];
  wnbf[i] = f2bf(Wfw[i] + s * (1.0f / 16384.0f));
}

extern "C" void kernel_launch(void* const* d_in, const int* in_sizes, int n_in,
                              void* d_out, int out_size, void* d_ws, size_t ws_size,
                              hipStream_t stream) {
  (void)in_sizes; (void)n_in; (void)out_size;
  const float* x   = (const float*)d_in[0];
  const float* Wsw = (const float*)d_in[1];
  const float* Wsb = (const float*)d_in[2];
  const float* Wfw = (const float*)d_in[3];
  const float* Wfb = (const float*)d_in[4];
  float* out = (float*)d_out;

  const size_t MB = 1ull << 20;
  int nc;
  if      (ws_size >= 216 * MB) nc = 1;
  else if (ws_size >= 164 * MB) nc = 2;
  else if (ws_size >= 122 * MB) nc = 4;
  else                          nc = 8;
  const size_t Bc = BATCH / nc;
  const int BcI = (int)Bc;
  const int zc = 8 / nc;
  const size_t CB = Bc * 1024 * 2;

  char* p = (char*)d_ws;
  size_t off = 0;
  auto alloc = [&](size_t bytes) {
    char* cur = p + off;
    off = (off + bytes + 255) & ~(size_t)255;
    return cur;
  };
  unsigned short* wbf  = (unsigned short*)alloc(3072ull * 1024 * 2);
  unsigned short* wfbf = (unsigned short*)alloc(1024ull * 1024 * 2);
  unsigned short* wnbf = (unsigned short*)alloc(1024ull * 1024 * 2);
  float*          lr   = (float*)alloc(BATCH * 4);
  unsigned short* qsm  = (unsigned short*)alloc((size_t)BATCH * 1024 * 2);

  unsigned short *xbf, *ksm, *kt, *Ut, *vT, *qt, *SKt;
  float* P;
  if (nc == 1) {
    char* rA = alloc(CB);  // xbf | ksm
    char* rB = alloc(CB);  // kt  | Ut
    char* rC = alloc(CB);  // vT  | P (slices 0-7)
    char* rD = alloc(CB);  // qt  | P (slices 8-15)   (rC,rD contiguous: CB is 256-aligned)
    char* rE = alloc(CB);  // SKt
    xbf = (unsigned short*)rA; ksm = (unsigned short*)rA;
    kt  = (unsigned short*)rB; Ut  = (unsigned short*)rB;
    vT  = (unsigned short*)rC;
    qt  = (unsigned short*)rD;
    P   = (float*)rC;      // 16 x 4MB = 64MB over rC..rD (vT,qt dead by then)
    SKt = (unsigned short*)rE;
  } else {
    P   = (float*)alloc(32 * MB);
    char* rA = alloc(CB);
    char* rB = alloc(CB);
    xbf = (unsigned short*)rA; ksm = (unsigned short*)rA;
    kt  = (unsigned short*)rB; Ut  = (unsigned short*)rB;
    vT  = (unsigned short*)alloc(CB);
    qt  = (unsigned short*)alloc(CB);
    SKt = (unsigned short*)alloc(CB);
  }

  cvt_bf<<<dim3(3072), 256, 0, stream>>>(Wsw, wbf);
  cvt_bf<<<dim3(1024), 256, 0, stream>>>(Wfw, wfbf);

  for (int c = 0; c < nc; c++) {
    const float* xc = x + (size_t)c * Bc * 1024;
    float* lrc = lr + (size_t)c * Bc;
    lrx<<<dim3((unsigned)(Bc / 4)), 256, 0, stream>>>(xc, Wsw, Wsb, lrc, xbf);
    // s = x @ Wslow^T + b  ->  kt | vT | qt   (all bf16 transposed [f][b])
    mgemm8<0><<<dim3(12, (unsigned)(Bc / 256)), 512, 0, stream>>>(
        xbf, wbf, 1024, 1024, Wsb, kt, vT, qt, nullptr, nullptr, nullptr,
        nullptr, BcI);
    // softmax(k) -> ksm [b][1024];  sigmoid(k)^T -> SKt [f][b]
    tsoftmax<true><<<dim3((unsigned)(Bc / 16)), 256, 0, stream>>>(
        kt, BcI, ksm, SKt, BcI);
    // softmax(q) -> qsm rows (persistent, row-major)
    tsoftmax<false><<<dim3((unsigned)(Bc / 16)), 256, 0, stream>>>(
        qt, BcI, qsm + (size_t)c * Bc * 1024, nullptr, BcI);
    // Ut[o][b] = bf16( lr * (v - (softmax(k) @ Wfw^T + Wfb)) )
    mgemm8<1><<<dim3(4, (unsigned)(Bc / 256)), 512, 0, stream>>>(
        ksm, wfbf, 1024, 1024, Wfb, nullptr, nullptr, nullptr, nullptr,
        vT, lrc, Ut, BcI);
    if (nc == 1) {
      // P[z] = Ut @ SKt^T over K-slice z*1024 (16 slices, 256 blocks = 1 round)
      mgemm8<3><<<dim3(4, 4, 16), 512, 0, stream>>>(
          Ut, SKt, BcI, BcI, nullptr, nullptr, nullptr, nullptr,
          P, nullptr, nullptr, nullptr, BcI);
    } else {
      mgemm<3><<<dim3(8, 8, zc), 256, 0, stream>>>(
          Ut, SKt, BcI, BcI, 2048, nullptr, nullptr, nullptr, nullptr,
          P + (size_t)c * zc * 1024 * 1024, nullptr, nullptr, nullptr, BcI);
    }
  }

  if (nc == 1)
    wnewk<16><<<dim3(1024 * 1024 / 256), 256, 0, stream>>>(P, Wfw, wnbf);
  else
    wnewk<8><<<dim3(1024 * 1024 / 256), 256, 0, stream>>>(P, Wfw, wnbf);

  // out = softmax(q) @ Wnew^T + Wfb   (fp32 row-major)
  mgemm8<2><<<dim3(4, BATCH / 256), 512, 0, stream>>>(
      qsm, wnbf, 1024, 1024, Wfb, nullptr, nullptr, nullptr, out,
      nullptr, nullptr, nullptr, 0);
}